// Round 3
// baseline (150.548 us; speedup 1.0000x reference)
//
#include <hip/hip_runtime.h>
#include <stdint.h>

// SelfAttention: B=4, T=2048, EMB=1024, causal + key padding (last 256 keys)
#define TB 2048
#define DD 1024

typedef __bf16 bf16x8 __attribute__((ext_vector_type(8)));
typedef float  f32x16 __attribute__((ext_vector_type(16)));
typedef int    int4v  __attribute__((ext_vector_type(4)));

__device__ __forceinline__ unsigned pack2(float hi, float lo) {
  return (__float_as_uint(hi) & 0xffff0000u) | (__float_as_uint(lo) >> 16);
}
__device__ __forceinline__ bf16x8 pack8(const float f[8]) {
  int4v w;
  w.x = (int)pack2(f[1], f[0]);
  w.y = (int)pack2(f[3], f[2]);
  w.z = (int)pack2(f[5], f[4]);
  w.w = (int)pack2(f[7], f[6]);
  return __builtin_bit_cast(int4v, w), __builtin_bit_cast(bf16x8, w);
}

// ============================ pre-pass kernels ============================
// Frag layout: [b][t32=T/32][ds=D/16][lane=64][8] bf16
//   element (b, 32*t32 + (lane&31), 16*ds + 8*(lane>>5) + j)
// Blocks 0..255 convert K (scale 1), blocks 256..511 convert Q (scale 1/32).
__global__ __launch_bounds__(256)
void conv_qk_bf16(const float* __restrict__ K, const float* __restrict__ Q,
                  unsigned short* __restrict__ Kf, unsigned short* __restrict__ Qf) {
  const int isQ = blockIdx.x >> 8;
  const int bid = blockIdx.x & 255;
  const float* src0 = isQ ? Q : K;
  unsigned short* dst0 = isQ ? Qf : Kf;
  const float scl = isQ ? 0.03125f : 1.0f;
  const int b  = bid >> 6;
  const int kt = bid & 63;
  const int lt  = threadIdx.x & 63;
  const int row = lt & 31, hi = lt >> 5;
  const int wv  = threadIdx.x >> 6;            // 0..3
  const float* src = src0 + ((size_t)(b * TB + kt * 32 + row)) * DD + hi * 8;
  unsigned short* dst = dst0 + ((size_t)(b * 64 + kt) * 64) * 512 + lt * 8;
  #pragma unroll
  for (int i = 0; i < 16; ++i) {
    const int ds = wv + 4 * i;
    const float4 a = *(const float4*)(src + ds * 16);
    const float4 c = *(const float4*)(src + ds * 16 + 4);
    const float f[8] = {a.x * scl, a.y * scl, a.z * scl, a.w * scl,
                        c.x * scl, c.y * scl, c.z * scl, c.w * scl};
    *(int4v*)(dst + (size_t)ds * 512) = __builtin_bit_cast(int4v, pack8(f));
  }
}

// Vf layout: [b][dt=D/32][ks=T/16][lane=64][8]  (bf16, transposed)
//   element = V[b][16*ks + 8*(lane>>5) + j][32*dt + (lane&31)]
__global__ __launch_bounds__(256)
void conv_v_bf16t(const float* __restrict__ V, unsigned short* __restrict__ Vf) {
  __shared__ __align__(16) float t[64 * 260];
  const int bid = blockIdx.x;
  const int b   = bid >> 7;
  const int kb  = (bid >> 2) & 31;
  const int db  = bid & 3;
  const int k0 = kb * 64, d0 = db * 256;
  {
    const int f = threadIdx.x & 63;
    const int r0 = threadIdx.x >> 6;
    #pragma unroll
    for (int i = 0; i < 16; ++i) {
      const int kloc = r0 + 4 * i;
      const float4 v4 = *(const float4*)(V + ((size_t)(b * TB + k0 + kloc)) * DD + d0 + f * 4);
      *(float4*)(t + kloc * 260 + f * 4) = v4;
    }
  }
  __syncthreads();
  const int lt  = threadIdx.x & 63;
  const int lo5 = lt & 31, hi = lt >> 5;
  const int kk  = threadIdx.x >> 6;
  #pragma unroll
  for (int dd = 0; dd < 8; ++dd) {
    float f[8];
    #pragma unroll
    for (int j = 0; j < 8; ++j)
      f[j] = t[(kk * 16 + hi * 8 + j) * 260 + dd * 32 + lo5];
    unsigned short* dst = Vf +
        (((size_t)(b * 32 + (d0 >> 5) + dd) * 128 + (k0 >> 4) + kk) * 64 + lt) * 8;
    *(int4v*)dst = __builtin_bit_cast(int4v, pack8(f));
  }
}

// ============================ main kernel (v3) ============================
// Grid 512: block = (b, 32-row q-tile, key-half h). Key tiles kt = h, h+2, ...
// Produces unnormalized O~ (h=0 -> Opart=d_out, h=1 -> OB) plus (m, l) in ML.
// ML layout: [h][ {m,l} ][ b*2048 + q ]  (4 * 8192 floats)
__global__ __launch_bounds__(512, 4)
void fa_fwd_f32_v3(const unsigned short* __restrict__ Qf, const int* __restrict__ AM,
                   const unsigned short* __restrict__ Kf,
                   const unsigned short* __restrict__ Vf,
                   float* __restrict__ OA, float* __restrict__ OB,
                   float* __restrict__ ML)
{
  __shared__ __align__(16) float lds_S[32 * 260];               // 33280 B
  __shared__ __align__(16) unsigned short lds_P[2][32 * 256];   // 32768 B (dbuf, XOR swz)
  __shared__ float lds_m[32], lds_l[32], lds_scale[32];
  __shared__ unsigned lds_mask32[TB / 4];
  __shared__ int lds_tv[8];

  const int tid  = threadIdx.x;
  const int w    = tid >> 6;
  const int lane = tid & 63;
  const int lo5  = lane & 31;
  const int hi   = lane >> 5;

  // XCD-chunked mapping: same (b,qt) pair's two halves land on same XCD.
  const int bid   = blockIdx.x;
  const int xcd   = bid & 7;
  const int slot  = bid >> 3;          // 0..63
  const int b     = xcd >> 1;
  const int halfq = xcd & 1;
  const int qi    = slot >> 1;         // 0..31
  const int h     = slot & 1;          // key-half
  const int qt    = halfq ? (16 + qi) : (qi < 16 ? qi : 32 + qi);
  const int q0    = qt << 5;

  // ---- stage padding mask + init ----
  const int4v mi = *(const int4v*)(AM + b * TB + 4 * tid);
  const unsigned mw = (mi.x ? 1u : 0u) | (mi.y ? 0x100u : 0u) |
                      (mi.z ? 0x10000u : 0u) | (mi.w ? 0x1000000u : 0u);
  lds_mask32[tid] = mw;
  if (tid < 8)  lds_tv[tid] = 0;
  if (tid < 32) { lds_m[tid] = -1e30f; lds_l[tid] = 0.0f; }
  __syncthreads();
  if (mw) lds_tv[tid >> 6] = 1;

  f32x16 oacc[4] = {f32x16{}, f32x16{}, f32x16{}, f32x16{}};

  const char* qf_w    = (const char*)Qf + ((size_t)(b * 64 + qt)) * 65536 + lane * 16;
  const char* kf_wave = (const char*)Kf + ((size_t)b * 64 + w) * 65536 + lane * 16;
  const char* vf_b    = (const char*)Vf + (size_t)b * 4194304 + (size_t)(w * 4) * 131072 + lane * 16;

  __syncthreads();

  const int nkt = (qt >> 3) + 1;
  int pcnt = 0;
  for (int kt = h; kt < nkt; kt += 2) {
    if (!lds_tv[kt]) continue;
    const int k0 = kt << 8;
    char* pb = (char*)lds_P + (pcnt & 1) * 16384;

    // ---- QK^T: wave w, keys k0+32w..+31, full d (64 MFMA, 2 chains) ----
    f32x16 s0{}, s1{};
    {
      const char* kp = kf_wave + (size_t)kt * 524288;
      const char* qp = qf_w;
      __builtin_amdgcn_s_setprio(1);
      #pragma unroll 8
      for (int ds = 0; ds < 64; ds += 2) {
        const bf16x8 a0 = *(const bf16x8*)qp;
        const bf16x8 b0 = *(const bf16x8*)kp;
        const bf16x8 a1 = *(const bf16x8*)(qp + 1024);
        const bf16x8 b1 = *(const bf16x8*)(kp + 1024);
        s0 = __builtin_amdgcn_mfma_f32_32x32x16_bf16(a0, b0, s0, 0, 0, 0);
        s1 = __builtin_amdgcn_mfma_f32_32x32x16_bf16(a1, b1, s1, 0, 0, 0);
        qp += 2048; kp += 2048;
      }
      __builtin_amdgcn_s_setprio(0);
    }
    #pragma unroll
    for (int reg = 0; reg < 16; ++reg) {
      const int row = (reg & 3) + ((reg >> 2) << 3) + (hi << 2);
      lds_S[row * 260 + (w << 5) + lo5] = s0[reg] + s1[reg];
    }
    __syncthreads();   // bar1: S complete

    // ---- softmax: thread (r = tid>>4, g = tid&15) covers keys 16g..16g+15 ----
    {
      const int r = tid >> 4, g = tid & 15;
      float s[16];
      *(float4*)(s + 0)  = *(const float4*)(lds_S + r * 260 + g * 16 + 0);
      *(float4*)(s + 4)  = *(const float4*)(lds_S + r * 260 + g * 16 + 4);
      *(float4*)(s + 8)  = *(const float4*)(lds_S + r * 260 + g * 16 + 8);
      *(float4*)(s + 12) = *(const float4*)(lds_S + r * 260 + g * 16 + 12);
      const int q = q0 + r;
      #pragma unroll
      for (int i = 0; i < 16; ++i) {
        const unsigned mword = lds_mask32[(k0 >> 2) + 4 * g + (i >> 2)];
        const bool ok = (((mword >> (8 * (i & 3))) & 0xffu) != 0u) && (k0 + 16 * g + i <= q);
        if (!ok) s[i] = -1e30f;
      }
      float mx = s[0];
      #pragma unroll
      for (int i = 1; i < 16; ++i) mx = fmaxf(mx, s[i]);
      #pragma unroll
      for (int d = 1; d < 16; d <<= 1) mx = fmaxf(mx, __shfl_xor(mx, d, 64));
      const float mold = lds_m[r];
      const float mnew = fmaxf(mold, mx);
      float p[16], ls = 0.f;
      #pragma unroll
      for (int i = 0; i < 16; ++i) { p[i] = __expf(s[i] - mnew); ls += p[i]; }
      #pragma unroll
      for (int d = 1; d < 16; d <<= 1) ls += __shfl_xor(ls, d, 64);
      if (g == 0) {
        const float resc = __expf(mold - mnew);
        lds_m[r]     = mnew;
        lds_l[r]     = lds_l[r] * resc + ls;
        lds_scale[r] = resc;
      }
      int4v w0, w1;
      w0.x = (int)pack2(p[1],  p[0]);  w0.y = (int)pack2(p[3],  p[2]);
      w0.z = (int)pack2(p[5],  p[4]);  w0.w = (int)pack2(p[7],  p[6]);
      w1.x = (int)pack2(p[9],  p[8]);  w1.y = (int)pack2(p[11], p[10]);
      w1.z = (int)pack2(p[13], p[12]); w1.w = (int)pack2(p[15], p[14]);
      *(int4v*)(pb + ((r * 512 + g * 32 + 0)  ^ ((r & 15) << 4))) = w0;
      *(int4v*)(pb + ((r * 512 + g * 32 + 16) ^ ((r & 15) << 4))) = w1;
    }
    __syncthreads();   // bar2: P + scale complete

    // ---- rescale O, then P x V ----
    {
      float sc[16];
      #pragma unroll
      for (int reg = 0; reg < 16; ++reg)
        sc[reg] = lds_scale[(reg & 3) + ((reg >> 2) << 3) + (hi << 2)];
      #pragma unroll
      for (int nb = 0; nb < 4; ++nb)
        #pragma unroll
        for (int reg = 0; reg < 16; ++reg) oacc[nb][reg] *= sc[reg];

      const char* vp0 = vf_b + (size_t)kt * 16384;
      __builtin_amdgcn_s_setprio(1);
      #pragma unroll 4
      for (int kc = 0; kc < 16; ++kc) {
        const bf16x8 pa = *(const bf16x8*)(pb +
            ((lo5 * 512 + kc * 32 + hi * 16) ^ ((lo5 & 15) << 4)));
        const char* vp = vp0 + kc * 1024;
        #pragma unroll
        for (int nb = 0; nb < 4; ++nb)
          oacc[nb] = __builtin_amdgcn_mfma_f32_32x32x16_bf16(
              pa, *(const bf16x8*)(vp + (size_t)nb * 131072), oacc[nb], 0, 0, 0);
      }
      __builtin_amdgcn_s_setprio(0);
    }
    ++pcnt;
    // no 3rd barrier: next S write is after bar2; P is double-buffered.
  }

  // ---- epilogue: store unnormalized O~ and (m, l) ----
  float* opart = (h ? OB : OA) + ((size_t)b * TB + q0) * DD + w * 128;
  #pragma unroll
  for (int nb = 0; nb < 4; ++nb) {
    #pragma unroll
    for (int reg = 0; reg < 16; ++reg) {
      const int row = (reg & 3) + ((reg >> 2) << 3) + (hi << 2);
      opart[(size_t)row * DD + nb * 32 + lo5] = oacc[nb][reg];
    }
  }
  if (tid < 32) {
    const int r = b * TB + q0 + tid;
    ML[h * 16384 + r]        = lds_m[tid];
    ML[h * 16384 + 8192 + r] = lds_l[tid];
  }
}

// ============================ merge kernel ============================
// O = (eA*OA~ + eB*OB~) / (eA*lA + eB*lB),  e{A,B} = exp(m{A,B} - max)
__global__ __launch_bounds__(256)
void merge_halves(float* __restrict__ O, const float* __restrict__ OB,
                  const float* __restrict__ ML) {
  const int idx = blockIdx.x * 256 + threadIdx.x;   // 524288 threads, 16 floats each
  const int row = idx >> 6;
  const float mA = ML[row],         lA = ML[8192 + row];
  const float mB = ML[16384 + row], lB = ML[24576 + row];
  const float m  = fmaxf(mA, mB);
  const float eA = __expf(mA - m), eB = __expf(mB - m);
  const float inv = 1.0f / (eA * lA + eB * lB);
  const float as = eA * inv, bs = eB * inv;
  float4* o4 = (float4*)O + (size_t)idx * 4;
  const float4* b4 = (const float4*)OB + (size_t)idx * 4;
  #pragma unroll
  for (int i = 0; i < 4; ++i) {
    float4 a = o4[i];
    const float4 bb = b4[i];
    a.x = a.x * as + bb.x * bs;
    a.y = a.y * as + bb.y * bs;
    a.z = a.z * as + bb.z * bs;
    a.w = a.w * as + bb.w * bs;
    o4[i] = a;
  }
}

// ============================ fallback (v2, known good) ============================
__global__ __launch_bounds__(512, 2)
void fa_fwd_f32_v2(const float* __restrict__ Q, const int* __restrict__ AM,
                   const unsigned short* __restrict__ Kf,
                   const unsigned short* __restrict__ Vf,
                   float* __restrict__ O)
{
  __shared__ __align__(16) unsigned short lds_Q[64 * 64 * 8];
  __shared__ __align__(16) float lds_S[32 * 260];
  __shared__ __align__(16) unsigned short lds_P[32 * 256];
  __shared__ float lds_m[32], lds_l[32], lds_scale[32];
  __shared__ unsigned lds_mask32[TB / 4];
  __shared__ int lds_tv[8];

  const int tid  = threadIdx.x;
  const int w    = tid >> 6;
  const int lane = tid & 63;
  const int lo5  = lane & 31;
  const int hi   = lane >> 5;

  const int bid  = blockIdx.x;
  const int xcd  = bid & 7;
  const int slot = bid >> 3;
  const int b    = xcd >> 1;
  const int half = xcd & 1;
  const int qt   = half ? (16 + slot) : (slot < 16 ? slot : 32 + slot);
  const int q0   = qt << 5;

  const int4v mi = *(const int4v*)(AM + b * TB + 4 * tid);
  const unsigned mw = (mi.x ? 1u : 0u) | (mi.y ? 0x100u : 0u) |
                      (mi.z ? 0x10000u : 0u) | (mi.w ? 0x1000000u : 0u);
  lds_mask32[tid] = mw;
  if (tid < 8)  lds_tv[tid] = 0;
  if (tid < 32) { lds_m[tid] = -1e30f; lds_l[tid] = 0.0f; }
  __syncthreads();
  if (mw) lds_tv[tid >> 6] = 1;

  {
    const int row = lane & 31, qhi = lane >> 5;
    const float* qsrc = Q + ((size_t)(b * TB + q0 + row)) * DD + qhi * 8;
    #pragma unroll
    for (int i = 0; i < 8; ++i) {
      const int ds = w + 8 * i;
      const float4 a = *(const float4*)(qsrc + ds * 16);
      const float4 c = *(const float4*)(qsrc + ds * 16 + 4);
      const float f[8] = {a.x * 0.03125f, a.y * 0.03125f, a.z * 0.03125f, a.w * 0.03125f,
                          c.x * 0.03125f, c.y * 0.03125f, c.z * 0.03125f, c.w * 0.03125f};
      *(int4v*)(lds_Q + (((size_t)ds << 6 | lane) << 3)) = __builtin_bit_cast(int4v, pack8(f));
    }
  }

  f32x16 oacc[4] = {f32x16{}, f32x16{}, f32x16{}, f32x16{}};
  const char* kf_wave = (const char*)Kf + ((size_t)b * 64 + w) * 65536 + lane * 16;
  const char* vf_b    = (const char*)Vf + (size_t)b * 4194304 + (size_t)(w * 4) * 131072 + lane * 16;
  const char* pbytes  = (const char*)lds_P;
  __syncthreads();

  const int nkt = (qt >> 3) + 1;
  for (int kt = 0; kt < nkt; ++kt) {
    if (!lds_tv[kt]) continue;
    const int k0 = kt << 8;
    f32x16 s0{}, s1{};
    {
      const char* kp = kf_wave + (size_t)kt * 524288;
      #pragma unroll 4
      for (int ds = 0; ds < 64; ds += 2) {
        const bf16x8 a0 = *(const bf16x8*)((const char*)lds_Q + ((ds << 6 | lane) << 4));
        const bf16x8 b0 = *(const bf16x8*)kp;
        const bf16x8 a1 = *(const bf16x8*)((const char*)lds_Q + (((ds + 1) << 6 | lane) << 4));
        const bf16x8 b1 = *(const bf16x8*)(kp + 1024);
        s0 = __builtin_amdgcn_mfma_f32_32x32x16_bf16(a0, b0, s0, 0, 0, 0);
        s1 = __builtin_amdgcn_mfma_f32_32x32x16_bf16(a1, b1, s1, 0, 0, 0);
        kp += 2048;
      }
    }
    #pragma unroll
    for (int reg = 0; reg < 16; ++reg) {
      const int row = (reg & 3) + ((reg >> 2) << 3) + (hi << 2);
      lds_S[row * 260 + (w << 5) + lo5] = s0[reg] + s1[reg];
    }
    __syncthreads();
    {
      const int r = tid >> 4, g = tid & 15;
      float s[16];
      *(float4*)(s + 0)  = *(const float4*)(lds_S + r * 260 + g * 16 + 0);
      *(float4*)(s + 4)  = *(const float4*)(lds_S + r * 260 + g * 16 + 4);
      *(float4*)(s + 8)  = *(const float4*)(lds_S + r * 260 + g * 16 + 8);
      *(float4*)(s + 12) = *(const float4*)(lds_S + r * 260 + g * 16 + 12);
      const int q = q0 + r;
      #pragma unroll
      for (int i = 0; i < 16; ++i) {
        const unsigned mword = lds_mask32[(k0 >> 2) + 4 * g + (i >> 2)];
        const bool ok = (((mword >> (8 * (i & 3))) & 0xffu) != 0u) && (k0 + 16 * g + i <= q);
        if (!ok) s[i] = -1e30f;
      }
      float mx = s[0];
      #pragma unroll
      for (int i = 1; i < 16; ++i) mx = fmaxf(mx, s[i]);
      #pragma unroll
      for (int d = 1; d < 16; d <<= 1) mx = fmaxf(mx, __shfl_xor(mx, d, 64));
      const float mold = lds_m[r];
      const float mnew = fmaxf(mold, mx);
      float p[16], ls = 0.f;
      #pragma unroll
      for (int i = 0; i < 16; ++i) { p[i] = __expf(s[i] - mnew); ls += p[i]; }
      #pragma unroll
      for (int d = 1; d < 16; d <<= 1) ls += __shfl_xor(ls, d, 64);
      if (g == 0) {
        const float resc = __expf(mold - mnew);
        lds_m[r]     = mnew;
        lds_l[r]     = lds_l[r] * resc + ls;
        lds_scale[r] = resc;
      }
      int4v w0, w1;
      w0.x = (int)pack2(p[1],  p[0]);  w0.y = (int)pack2(p[3],  p[2]);
      w0.z = (int)pack2(p[5],  p[4]);  w0.w = (int)pack2(p[7],  p[6]);
      w1.x = (int)pack2(p[9],  p[8]);  w1.y = (int)pack2(p[11], p[10]);
      w1.z = (int)pack2(p[13], p[12]); w1.w = (int)pack2(p[15], p[14]);
      char* pbw = (char*)lds_P;
      *(int4v*)(pbw + ((r * 512 + g * 32 + 0)  ^ ((r & 15) << 4))) = w0;
      *(int4v*)(pbw + ((r * 512 + g * 32 + 16) ^ ((r & 15) << 4))) = w1;
    }
    __syncthreads();
    {
      float sc[16];
      #pragma unroll
      for (int reg = 0; reg < 16; ++reg)
        sc[reg] = lds_scale[(reg & 3) + ((reg >> 2) << 3) + (hi << 2)];
      #pragma unroll
      for (int nb = 0; nb < 4; ++nb)
        #pragma unroll
        for (int reg = 0; reg < 16; ++reg) oacc[nb][reg] *= sc[reg];
      const char* vp0 = vf_b + (size_t)kt * 16384;
      #pragma unroll 4
      for (int kc = 0; kc < 16; ++kc) {
        const bf16x8 pa = *(const bf16x8*)(pbytes +
            ((lo5 * 512 + kc * 32 + hi * 16) ^ ((lo5 & 15) << 4)));
        const char* vp = vp0 + kc * 1024;
        #pragma unroll
        for (int nb = 0; nb < 4; ++nb)
          oacc[nb] = __builtin_amdgcn_mfma_f32_32x32x16_bf16(
              pa, *(const bf16x8*)(vp + (size_t)nb * 131072), oacc[nb], 0, 0, 0);
      }
    }
    __syncthreads();
  }

  float il[16];
  #pragma unroll
  for (int reg = 0; reg < 16; ++reg)
    il[reg] = 1.0f / lds_l[(reg & 3) + ((reg >> 2) << 3) + (hi << 2)];
  float* ob = O + ((size_t)b * TB + q0) * DD + w * 128;
  #pragma unroll
  for (int nb = 0; nb < 4; ++nb) {
    #pragma unroll
    for (int reg = 0; reg < 16; ++reg) {
      const int row = (reg & 3) + ((reg >> 2) << 3) + (hi << 2);
      ob[(size_t)row * DD + nb * 32 + lo5] = oacc[nb][reg] * il[reg];
    }
  }
}

extern "C" void kernel_launch(void* const* d_in, const int* in_sizes, int n_in,
                              void* d_out, int out_size, void* d_ws, size_t ws_size,
                              hipStream_t stream) {
  const float* Q  = (const float*)d_in[0];
  const float* K  = (const float*)d_in[1];
  const float* V  = (const float*)d_in[2];
  const int*   AM = (const int*)d_in[3];
  float* O = (float*)d_out;
  (void)in_sizes; (void)n_in; (void)out_size;

  const size_t kf_bytes = (size_t)16777216;   // K frags
  const size_t vf_bytes = (size_t)16777216;   // V frags
  const size_t qf_bytes = (size_t)16777216;   // Q frags
  const size_t ob_bytes = (size_t)TB * DD * 4 * 4;   // 33.55 MB partial B
  const size_t ml_bytes = (size_t)4 * 8192 * 4;      // 128 KB
  const size_t v3_need  = kf_bytes + vf_bytes + qf_bytes + ob_bytes + ml_bytes;

  unsigned short* Kf = (unsigned short*)d_ws;
  unsigned short* Vf = (unsigned short*)((char*)d_ws + kf_bytes);

  if (ws_size >= v3_need) {
    unsigned short* Qf = (unsigned short*)((char*)d_ws + kf_bytes + vf_bytes);
    float* OB = (float*)((char*)d_ws + kf_bytes + vf_bytes + qf_bytes);
    float* ML = (float*)((char*)d_ws + kf_bytes + vf_bytes + qf_bytes + ob_bytes);
    hipLaunchKernelGGL(conv_qk_bf16, dim3(512), dim3(256), 0, stream, K, Q, Kf, Qf);
    hipLaunchKernelGGL(conv_v_bf16t, dim3(512), dim3(256), 0, stream, V, Vf);
    hipLaunchKernelGGL(fa_fwd_f32_v3, dim3(512), dim3(512), 0, stream,
                       Qf, AM, Kf, Vf, O, OB, ML);
    hipLaunchKernelGGL(merge_halves, dim3(2048), dim3(256), 0, stream, O, OB, ML);
  } else if (ws_size >= kf_bytes + vf_bytes) {
    hipLaunchKernelGGL(conv_qk_bf16, dim3(256), dim3(256), 0, stream, K, Q, Kf, Kf);
    hipLaunchKernelGGL(conv_v_bf16t, dim3(512), dim3(256), 0, stream, V, Vf);
    hipLaunchKernelGGL(fa_fwd_f32_v2, dim3(256), dim3(512), 0, stream, Q, AM, Kf, Vf, O);
  }
}